// Round 4
// baseline (980.040 us; speedup 1.0000x reference)
//
#include <hip/hip_runtime.h>

typedef __bf16 bf16x4 __attribute__((ext_vector_type(4)));
typedef __bf16 bf16x8 __attribute__((ext_vector_type(8)));
typedef float f32x4 __attribute__((ext_vector_type(4)));

#define NBLOCKS 2048
#define MBLK 16
#define RSTRIDE 196   // f32 elems; rinv transpose row stride (196%32=4 -> writes spread banks)

__device__ __forceinline__ unsigned short f2bf(float f) {
    unsigned u = __float_as_uint(f);
    u += 0x7fffu + ((u >> 16) & 1u);
    return (unsigned short)(u >> 16);
}

// GT[d*192+c] = bf16(gs*relu(gamma[c][d]) + gb);  biasv[d] = bs*(relu(beta[d])+1e-6) + bb
__global__ void gdn_prep(const float* __restrict__ beta_raw,
                         const float* __restrict__ gamma_raw,
                         const float* __restrict__ beta_scale,
                         const float* __restrict__ beta_bias,
                         const float* __restrict__ gamma_scale,
                         const float* __restrict__ gamma_bias,
                         const int* __restrict__ idxp,
                         unsigned short* __restrict__ GT,
                         float* __restrict__ biasv)
{
    const int idx = idxp[0];
    const float gs = fmaxf(gamma_scale[idx], 0.f);
    const float gb = fmaxf(gamma_bias[idx], 0.f);
    int t = blockIdx.x * blockDim.x + threadIdx.x;  // 0..36863
    if (t < 192 * 192) {
        int c = t / 192;
        int d = t - c * 192;
        float g = fmaxf(gamma_raw[t], 0.f);
        GT[d * 192 + c] = f2bf(gs * g + gb);
    }
    if (t < 192) {
        const float bs = fmaxf(beta_scale[idx], 0.f);
        const float bb = fmaxf(beta_bias[idx], 0.f);
        float b = fmaxf(beta_raw[t], 0.f) + 1e-6f;
        biasv[t] = bs * b + bb;
    }
}

// 16-px tiles, 18.7 KB LDS -> 8 blocks/CU; depth-2 register prefetch (xa/xb/xc);
// launch_bounds(256,8): allow ~256 VGPR so Bf[3][6] (72 regs) stays RESIDENT
// instead of being re-fetched from global every iteration (round-1 VGPR_Count=80
// proved the compiler was starving the kernel).
__global__ __launch_bounds__(256, 8) void gdn_main(
    const float* __restrict__ x,
    const unsigned short* __restrict__ GT,
    const float* __restrict__ biasv,
    float* __restrict__ out,
    int ntiles)
{
    __shared__ __align__(16) unsigned char xsq[MBLK * 384];  // bf16 [16][192], XOR-swizzled
    __shared__ float lrinv[MBLK * RSTRIDE];                  // 12544 B

    const int tid = threadIdx.x;
    const int l   = tid & 63;
    const int w   = tid >> 6;
    const int l15 = l & 15;
    const int lq  = l >> 4;
    const int d0w = w * 48;            // wave owns d in [48w, 48w+48)
    const int rsw = (l15 & 7) << 4;    // frag-read XOR mask

    // B frag: B[k=c][n=d], lane: n=l15, k=lq*8+e  -> GT row (d), 16B contiguous
    bf16x8 Bf[3][6];
    {
        const unsigned short* g0 = GT + (d0w + l15) * 192 + lq * 8;
        #pragma unroll
        for (int j = 0; j < 3; ++j)
            #pragma unroll
            for (int kt = 0; kt < 6; ++kt)
                Bf[j][kt] = *(const bf16x8*)(g0 + j * (16 * 192) + kt * 32);
    }
    float biasl[3];
    #pragma unroll
    for (int j = 0; j < 3; ++j) biasl[j] = biasv[d0w + j * 16 + l15];

    // per-thread stage/epilogue mapping: f32x4 quad q = tid + 256*i (i<3),
    // row = q/48, quad-col = q%48; global addr = tile_base + 4*q (contiguous!)
    int swzb[3], lofs[3];
    #pragma unroll
    for (int i = 0; i < 3; ++i) {
        int q = tid + 256 * i;
        int r = q / 48;
        int c = q - r * 48;
        swzb[i] = r * 384 + ((c * 8) ^ ((r & 7) << 4));  // swizzled LDS byte addr (8B unit)
        lofs[i] = r * RSTRIDE + c * 4;                   // lrinv f32 index
    }

    f32x4 xa[3], xb[3], xc[3];  // x(t) [epilogue], x(t+NB) [stage], x(t+2NB) [in flight]

    // ---- prologue ----
    {
        const float* xp = x + (size_t)blockIdx.x * (MBLK * 192);
        #pragma unroll
        for (int i = 0; i < 3; ++i)
            xa[i] = __builtin_nontemporal_load((const f32x4*)(xp + tid * 4 + 1024 * i));
        #pragma unroll
        for (int i = 0; i < 3; ++i) {
            bf16x4 s;
            #pragma unroll
            for (int e = 0; e < 4; ++e) s[e] = (__bf16)(xa[i][e] * xa[i][e]);
            *(bf16x4*)(xsq + swzb[i]) = s;
        }
        if (blockIdx.x + NBLOCKS < ntiles) {
            const float* xq = x + (size_t)(blockIdx.x + NBLOCKS) * (MBLK * 192);
            #pragma unroll
            for (int i = 0; i < 3; ++i)
                xb[i] = __builtin_nontemporal_load((const f32x4*)(xq + tid * 4 + 1024 * i));
        }
    }
    __syncthreads();

    for (int tile = blockIdx.x; tile < ntiles; tile += NBLOCKS) {
        const bool hasB = (tile + NBLOCKS)     < ntiles;
        const bool hasC = (tile + 2 * NBLOCKS) < ntiles;

        // issue t+2 loads: consumed 1.5 iterations later -> latency fully covered
        if (hasC) {
            const float* xq = x + (size_t)(tile + 2 * NBLOCKS) * (MBLK * 192);
            #pragma unroll
            for (int i = 0; i < 3; ++i)
                xc[i] = __builtin_nontemporal_load((const f32x4*)(xq + tid * 4 + 1024 * i));
        }

        f32x4 acc[3];
        #pragma unroll
        for (int j = 0; j < 3; ++j) acc[j] = (f32x4){0.f, 0.f, 0.f, 0.f};

        // A frags from swizzled LDS: A[m=pixel=l15][k=lq*8+e (+32kt)]
        #pragma unroll
        for (int kt = 0; kt < 6; ++kt) {
            bf16x8 s = *(const bf16x8*)(xsq + l15 * 384 + ((kt * 64 + lq * 16) ^ rsw));
            #pragma unroll
            for (int j = 0; j < 3; ++j)
                acc[j] = __builtin_amdgcn_mfma_f32_16x16x32_bf16(s, Bf[j][kt], acc[j], 0, 0, 0);
        }

        __syncthreads();  // frag reads done -> xsq overwritable; prev epilogue lrinv reads done

        // rinv transpose: C/D col(d)=l15, row(pixel)=lq*4+r  (2-way bank alias: free)
        #pragma unroll
        for (int j = 0; j < 3; ++j)
            #pragma unroll
            for (int r = 0; r < 4; ++r)
                lrinv[(lq * 4 + r) * RSTRIDE + d0w + j * 16 + l15] =
                    __builtin_amdgcn_rsqf(acc[j][r] + biasl[j]);

        // stage next tile (loaded a full iteration ago -> no vmcnt stall)
        if (hasB) {
            #pragma unroll
            for (int i = 0; i < 3; ++i) {
                bf16x4 s;
                #pragma unroll
                for (int e = 0; e < 4; ++e) s[e] = (__bf16)(xb[i][e] * xb[i][e]);
                *(bf16x4*)(xsq + swzb[i]) = s;
            }
        }

        __syncthreads();  // lrinv + next xsq visible

        // epilogue: out = x(regs) * rinv, fully coalesced nt-stores
        {
            float* op = out + (size_t)tile * (MBLK * 192);
            #pragma unroll
            for (int i = 0; i < 3; ++i) {
                f32x4 rv = *(const f32x4*)&lrinv[lofs[i]];
                f32x4 o;
                #pragma unroll
                for (int h = 0; h < 4; ++h) o[h] = xa[i][h] * rv[h];
                __builtin_nontemporal_store(o, (f32x4*)(op + tid * 4 + 1024 * i));
            }
        }

        // rotate pipeline buffers
        #pragma unroll
        for (int i = 0; i < 3; ++i) { xa[i] = xb[i]; xb[i] = xc[i]; }
    }
}

extern "C" void kernel_launch(void* const* d_in, const int* in_sizes, int n_in,
                              void* d_out, int out_size, void* d_ws, size_t ws_size,
                              hipStream_t stream)
{
    const float* x           = (const float*)d_in[0];
    const float* beta_raw    = (const float*)d_in[1];
    const float* gamma_raw   = (const float*)d_in[2];
    const float* beta_scale  = (const float*)d_in[3];
    const float* beta_bias   = (const float*)d_in[4];
    const float* gamma_scale = (const float*)d_in[5];
    const float* gamma_bias  = (const float*)d_in[6];
    const int*   idxp        = (const int*)d_in[7];
    float*       out         = (float*)d_out;

    unsigned short* GT    = (unsigned short*)d_ws;
    float*          biasv = (float*)((char*)d_ws + 192 * 192 * sizeof(unsigned short));

    gdn_prep<<<144, 256, 0, stream>>>(beta_raw, gamma_raw, beta_scale, beta_bias,
                                      gamma_scale, gamma_bias, idxp, GT, biasv);

    const int P = out_size / 192;       // 524288 pixels
    const int ntiles = P / MBLK;        // 32768
    gdn_main<<<NBLOCKS, 256, 0, stream>>>(x, GT, biasv, out, ntiles);
}

// Round 5
// 664.946 us; speedup vs baseline: 1.4739x; 1.4739x over previous
//
#include <hip/hip_runtime.h>

typedef __bf16 bf16x4 __attribute__((ext_vector_type(4)));
typedef __bf16 bf16x8 __attribute__((ext_vector_type(8)));
typedef float f32x4 __attribute__((ext_vector_type(4)));

#define NBLOCKS 2048
#define MBLK 16
#define RSTRIDE 196   // f32 elems; lrinv row stride

__device__ __forceinline__ unsigned short f2bf(float f) {
    unsigned u = __float_as_uint(f);
    u += 0x7fffu + ((u >> 16) & 1u);
    return (unsigned short)(u >> 16);
}

// Raw barrier draining ONLY LDS ops: global prefetch loads stay in flight
// (hipcc's __syncthreads would emit s_waitcnt vmcnt(0) and kill the pipeline).
// All cross-wave communication in gdn_main is via LDS, so this is sufficient.
__device__ __forceinline__ void lds_barrier() {
    asm volatile("s_waitcnt lgkmcnt(0)" ::: "memory");
    __builtin_amdgcn_s_barrier();
}

// GT[d*192+c] = bf16(gs*relu(gamma[c][d]) + gb);  biasv[d] = bs*(relu(beta[d])+1e-6) + bb
__global__ void gdn_prep(const float* __restrict__ beta_raw,
                         const float* __restrict__ gamma_raw,
                         const float* __restrict__ beta_scale,
                         const float* __restrict__ beta_bias,
                         const float* __restrict__ gamma_scale,
                         const float* __restrict__ gamma_bias,
                         const int* __restrict__ idxp,
                         unsigned short* __restrict__ GT,
                         float* __restrict__ biasv)
{
    const int idx = idxp[0];
    const float gs = fmaxf(gamma_scale[idx], 0.f);
    const float gb = fmaxf(gamma_bias[idx], 0.f);
    int t = blockIdx.x * blockDim.x + threadIdx.x;  // 0..36863
    if (t < 192 * 192) {
        int c = t / 192;
        int d = t - c * 192;
        float g = fmaxf(gamma_raw[t], 0.f);
        GT[d * 192 + c] = f2bf(gs * g + gb);
    }
    if (t < 192) {
        const float bs = fmaxf(beta_scale[idx], 0.f);
        const float bb = fmaxf(beta_bias[idx], 0.f);
        float b = fmaxf(beta_raw[t], 0.f) + 1e-6f;
        biasv[t] = bs * b + bb;
    }
}

// 16-px tiles; double-buffered xsq+lrinv -> ONE lgkm-only barrier per iteration;
// depth-2 register prefetch (xa/xb/xc) survives across barriers (no vmcnt(0) drain).
// launch_bounds(256,3): VGPR cap ~170 so Bf[3][6] (72) + pipeline (36) stay resident
// with zero spills (round-4's (256,8) forced VGPR=32 -> spill disaster).
__global__ __launch_bounds__(256, 3) void gdn_main(
    const float* __restrict__ x,
    const unsigned short* __restrict__ GT,
    const float* __restrict__ biasv,
    float* __restrict__ out,
    int ntiles)
{
    __shared__ __align__(16) unsigned char xsq[2][MBLK * 384];  // bf16 [16][192] x2, XOR-swizzled
    __shared__ float lrinv[2][MBLK * RSTRIDE];                  // 2 x 12544 B

    const int tid = threadIdx.x;
    const int l   = tid & 63;
    const int w   = tid >> 6;
    const int l15 = l & 15;
    const int lq  = l >> 4;
    const int d0w = w * 48;            // wave owns d in [48w, 48w+48)
    const int rsw = (l15 & 7) << 4;    // frag-read XOR mask

    // B frag: B[k=c][n=d], lane: n=l15, k=lq*8+e  -> GT row (d), 16B contiguous
    bf16x8 Bf[3][6];
    {
        const unsigned short* g0 = GT + (d0w + l15) * 192 + lq * 8;
        #pragma unroll
        for (int j = 0; j < 3; ++j)
            #pragma unroll
            for (int kt = 0; kt < 6; ++kt)
                Bf[j][kt] = *(const bf16x8*)(g0 + j * (16 * 192) + kt * 32);
    }
    float biasl[3];
    #pragma unroll
    for (int j = 0; j < 3; ++j) biasl[j] = biasv[d0w + j * 16 + l15];

    // per-thread stage/epilogue mapping: f32x4 quad q = tid + 256*i (i<3),
    // row = q/48, quad-col = q%48; global addr = tile_base + 4*q (contiguous)
    int swzb[3], lofs[3];
    #pragma unroll
    for (int i = 0; i < 3; ++i) {
        int q = tid + 256 * i;
        int r = q / 48;
        int c = q - r * 48;
        swzb[i] = r * 384 + ((c * 8) ^ ((r & 7) << 4));  // swizzled LDS byte addr (8B unit)
        lofs[i] = r * RSTRIDE + c * 4;                   // lrinv f32 index
    }

    f32x4 xa[3], xb[3], xc[3];  // x(t) [epilogue], x(t+NB) [next stage], x(t+2NB) [in flight]

    // ---- prologue: xa + stage xsq[0]; issue xb ----
    {
        const float* xp = x + (size_t)blockIdx.x * (MBLK * 192);
        #pragma unroll
        for (int i = 0; i < 3; ++i)
            xa[i] = *(const f32x4*)(xp + tid * 4 + 1024 * i);
        #pragma unroll
        for (int i = 0; i < 3; ++i) {
            bf16x4 s;
            #pragma unroll
            for (int e = 0; e < 4; ++e) s[e] = (__bf16)(xa[i][e] * xa[i][e]);
            *(bf16x4*)(&xsq[0][0] + swzb[i]) = s;
        }
        // blockIdx.x + NBLOCKS < ntiles always (4095 < 32768): no guard
        const float* xq = x + (size_t)(blockIdx.x + NBLOCKS) * (MBLK * 192);
        #pragma unroll
        for (int i = 0; i < 3; ++i)
            xb[i] = *(const f32x4*)(xq + tid * 4 + 1024 * i);
    }
    lds_barrier();

    int b = 0;
    for (int tile = blockIdx.x; tile < ntiles; tile += NBLOCKS, b ^= 1) {
        const bool hasB = (tile + NBLOCKS)     < ntiles;
        const bool hasC = (tile + 2 * NBLOCKS) < ntiles;

        // issue t+2 loads: consumed by staging ~1.5 iterations later
        if (hasC) {
            const float* xq = x + (size_t)(tile + 2 * NBLOCKS) * (MBLK * 192);
            #pragma unroll
            for (int i = 0; i < 3; ++i)
                xc[i] = *(const f32x4*)(xq + tid * 4 + 1024 * i);
        }

        f32x4 acc[3];
        #pragma unroll
        for (int j = 0; j < 3; ++j) acc[j] = (f32x4){0.f, 0.f, 0.f, 0.f};

        // A frags from swizzled LDS buf b: A[m=pixel=l15][k=lq*8+e (+32kt)]
        const unsigned char* xs = &xsq[b][0];
        #pragma unroll
        for (int kt = 0; kt < 6; ++kt) {
            bf16x8 s = *(const bf16x8*)(xs + l15 * 384 + ((kt * 64 + lq * 16) ^ rsw));
            #pragma unroll
            for (int j = 0; j < 3; ++j)
                acc[j] = __builtin_amdgcn_mfma_f32_16x16x32_bf16(s, Bf[j][kt], acc[j], 0, 0, 0);
        }

        // stage next tile into the OTHER xsq buffer (pre-barrier; read next iter)
        if (hasB) {
            #pragma unroll
            for (int i = 0; i < 3; ++i) {
                bf16x4 s;
                #pragma unroll
                for (int e = 0; e < 4; ++e) s[e] = (__bf16)(xb[i][e] * xb[i][e]);
                *(bf16x4*)(&xsq[b ^ 1][0] + swzb[i]) = s;
            }
        }

        // rinv transpose into lrinv[b]: C/D col(d)=l15, row(pixel)=lq*4+r
        #pragma unroll
        for (int j = 0; j < 3; ++j)
            #pragma unroll
            for (int r = 0; r < 4; ++r)
                lrinv[b][(lq * 4 + r) * RSTRIDE + d0w + j * 16 + l15] =
                    __builtin_amdgcn_rsqf(acc[j][r] + biasl[j]);

        lds_barrier();  // the ONLY barrier: xsq[b^1] + lrinv[b] visible; xc stays in flight

        // epilogue: out = x(regs) * rinv, fully coalesced
        {
            float* op = out + (size_t)tile * (MBLK * 192);
            #pragma unroll
            for (int i = 0; i < 3; ++i) {
                f32x4 rv = *(const f32x4*)&lrinv[b][lofs[i]];
                f32x4 o;
                #pragma unroll
                for (int h = 0; h < 4; ++h) o[h] = xa[i][h] * rv[h];
                *(f32x4*)(op + tid * 4 + 1024 * i) = o;
            }
        }

        // rotate pipeline
        #pragma unroll
        for (int i = 0; i < 3; ++i) { xa[i] = xb[i]; xb[i] = xc[i]; }
    }
}

extern "C" void kernel_launch(void* const* d_in, const int* in_sizes, int n_in,
                              void* d_out, int out_size, void* d_ws, size_t ws_size,
                              hipStream_t stream)
{
    const float* x           = (const float*)d_in[0];
    const float* beta_raw    = (const float*)d_in[1];
    const float* gamma_raw   = (const float*)d_in[2];
    const float* beta_scale  = (const float*)d_in[3];
    const float* beta_bias   = (const float*)d_in[4];
    const float* gamma_scale = (const float*)d_in[5];
    const float* gamma_bias  = (const float*)d_in[6];
    const int*   idxp        = (const int*)d_in[7];
    float*       out         = (float*)d_out;

    unsigned short* GT    = (unsigned short*)d_ws;
    float*          biasv = (float*)((char*)d_ws + 192 * 192 * sizeof(unsigned short));

    gdn_prep<<<144, 256, 0, stream>>>(beta_raw, gamma_raw, beta_scale, beta_bias,
                                      gamma_scale, gamma_bias, idxp, GT, biasv);

    const int P = out_size / 192;       // 524288 pixels
    const int ntiles = P / MBLK;        // 32768
    gdn_main<<<NBLOCKS, 256, 0, stream>>>(x, GT, biasv, out, ntiles);
}

// Round 6
// 663.577 us; speedup vs baseline: 1.4769x; 1.0021x over previous
//
#include <hip/hip_runtime.h>

typedef __bf16 bf16x4 __attribute__((ext_vector_type(4)));
typedef __bf16 bf16x8 __attribute__((ext_vector_type(8)));
typedef float f32x4 __attribute__((ext_vector_type(4)));

#define NBLOCKS 2048
#define MBLK 16
#define RSTRIDE 196   // f32 elems; lrinv row stride

__device__ __forceinline__ unsigned short f2bf(float f) {
    unsigned u = __float_as_uint(f);
    u += 0x7fffu + ((u >> 16) & 1u);
    return (unsigned short)(u >> 16);
}

// Raw barrier draining ONLY LDS ops: global prefetch loads stay in flight.
__device__ __forceinline__ void lds_barrier() {
    asm volatile("s_waitcnt lgkmcnt(0)" ::: "memory");
    __builtin_amdgcn_s_barrier();
}

// GT[d*192+c] = bf16(gs*relu(gamma[c][d]) + gb);  biasv[d] = bs*(relu(beta[d])+1e-6) + bb
__global__ void gdn_prep(const float* __restrict__ beta_raw,
                         const float* __restrict__ gamma_raw,
                         const float* __restrict__ beta_scale,
                         const float* __restrict__ beta_bias,
                         const float* __restrict__ gamma_scale,
                         const float* __restrict__ gamma_bias,
                         const int* __restrict__ idxp,
                         unsigned short* __restrict__ GT,
                         float* __restrict__ biasv)
{
    const int idx = idxp[0];
    const float gs = fmaxf(gamma_scale[idx], 0.f);
    const float gb = fmaxf(gamma_bias[idx], 0.f);
    int t = blockIdx.x * blockDim.x + threadIdx.x;  // 0..36863
    if (t < 192 * 192) {
        int c = t / 192;
        int d = t - c * 192;
        float g = fmaxf(gamma_raw[t], 0.f);
        GT[d * 192 + c] = f2bf(gs * g + gb);
    }
    if (t < 192) {
        const float bs = fmaxf(beta_scale[idx], 0.f);
        const float bb = fmaxf(beta_bias[idx], 0.f);
        float b = fmaxf(beta_raw[t], 0.f) + 1e-6f;
        biasv[t] = bs * b + bb;
    }
}

// Round-5 body UNCHANGED except the phase-stagger prologue:
// the 4 blocks resident on a CU get ~0/4K/8K/12K-cycle offsets so their
// vmem bursts tile the iteration period instead of coinciding (lockstep-burst
// theory: rounds 1/3/5 all plateau at ~6.4 B/cy/CU vs copy's 10.25).
__global__ __launch_bounds__(256, 3) void gdn_main(
    const float* __restrict__ x,
    const unsigned short* __restrict__ GT,
    const float* __restrict__ biasv,
    float* __restrict__ out,
    int ntiles)
{
    __shared__ __align__(16) unsigned char xsq[2][MBLK * 384];  // bf16 [16][192] x2, XOR-swizzled
    __shared__ float lrinv[2][MBLK * RSTRIDE];                  // 2 x 12544 B

    // ---- phase stagger: first batch only; CU's 4 resident blocks are
    // (bid, bid+256, bid+512, bid+768) -> slot = (bid>>8)&3 ----
    {
        const int slot = (blockIdx.x < 1024) ? ((blockIdx.x >> 8) & 3) : 0;
        for (int i = 0; i < slot * 2; ++i)
            __builtin_amdgcn_s_sleep(32);   // ~2048 cycles each
    }

    const int tid = threadIdx.x;
    const int l   = tid & 63;
    const int w   = tid >> 6;
    const int l15 = l & 15;
    const int lq  = l >> 4;
    const int d0w = w * 48;            // wave owns d in [48w, 48w+48)
    const int rsw = (l15 & 7) << 4;    // frag-read XOR mask

    // B frag: B[k=c][n=d], lane: n=l15, k=lq*8+e  -> GT row (d), 16B contiguous
    bf16x8 Bf[3][6];
    {
        const unsigned short* g0 = GT + (d0w + l15) * 192 + lq * 8;
        #pragma unroll
        for (int j = 0; j < 3; ++j)
            #pragma unroll
            for (int kt = 0; kt < 6; ++kt)
                Bf[j][kt] = *(const bf16x8*)(g0 + j * (16 * 192) + kt * 32);
    }
    float biasl[3];
    #pragma unroll
    for (int j = 0; j < 3; ++j) biasl[j] = biasv[d0w + j * 16 + l15];

    // per-thread stage/epilogue mapping: f32x4 quad q = tid + 256*i (i<3),
    // row = q/48, quad-col = q%48; global addr = tile_base + 4*q (contiguous)
    int swzb[3], lofs[3];
    #pragma unroll
    for (int i = 0; i < 3; ++i) {
        int q = tid + 256 * i;
        int r = q / 48;
        int c = q - r * 48;
        swzb[i] = r * 384 + ((c * 8) ^ ((r & 7) << 4));  // swizzled LDS byte addr (8B unit)
        lofs[i] = r * RSTRIDE + c * 4;                   // lrinv f32 index
    }

    f32x4 xa[3], xb[3], xc[3];  // x(t) [epilogue], x(t+NB) [next stage], x(t+2NB) [in flight]

    // ---- prologue: xa + stage xsq[0]; issue xb ----
    {
        const float* xp = x + (size_t)blockIdx.x * (MBLK * 192);
        #pragma unroll
        for (int i = 0; i < 3; ++i)
            xa[i] = *(const f32x4*)(xp + tid * 4 + 1024 * i);
        #pragma unroll
        for (int i = 0; i < 3; ++i) {
            bf16x4 s;
            #pragma unroll
            for (int e = 0; e < 4; ++e) s[e] = (__bf16)(xa[i][e] * xa[i][e]);
            *(bf16x4*)(&xsq[0][0] + swzb[i]) = s;
        }
        // blockIdx.x + NBLOCKS < ntiles always (4095 < 32768): no guard
        const float* xq = x + (size_t)(blockIdx.x + NBLOCKS) * (MBLK * 192);
        #pragma unroll
        for (int i = 0; i < 3; ++i)
            xb[i] = *(const f32x4*)(xq + tid * 4 + 1024 * i);
    }
    lds_barrier();

    int b = 0;
    for (int tile = blockIdx.x; tile < ntiles; tile += NBLOCKS, b ^= 1) {
        const bool hasB = (tile + NBLOCKS)     < ntiles;
        const bool hasC = (tile + 2 * NBLOCKS) < ntiles;

        // issue t+2 loads: consumed by staging ~1.5 iterations later
        if (hasC) {
            const float* xq = x + (size_t)(tile + 2 * NBLOCKS) * (MBLK * 192);
            #pragma unroll
            for (int i = 0; i < 3; ++i)
                xc[i] = *(const f32x4*)(xq + tid * 4 + 1024 * i);
        }

        f32x4 acc[3];
        #pragma unroll
        for (int j = 0; j < 3; ++j) acc[j] = (f32x4){0.f, 0.f, 0.f, 0.f};

        // A frags from swizzled LDS buf b: A[m=pixel=l15][k=lq*8+e (+32kt)]
        const unsigned char* xs = &xsq[b][0];
        #pragma unroll
        for (int kt = 0; kt < 6; ++kt) {
            bf16x8 s = *(const bf16x8*)(xs + l15 * 384 + ((kt * 64 + lq * 16) ^ rsw));
            #pragma unroll
            for (int j = 0; j < 3; ++j)
                acc[j] = __builtin_amdgcn_mfma_f32_16x16x32_bf16(s, Bf[j][kt], acc[j], 0, 0, 0);
        }

        // stage next tile into the OTHER xsq buffer (pre-barrier; read next iter)
        if (hasB) {
            #pragma unroll
            for (int i = 0; i < 3; ++i) {
                bf16x4 s;
                #pragma unroll
                for (int e = 0; e < 4; ++e) s[e] = (__bf16)(xb[i][e] * xb[i][e]);
                *(bf16x4*)(&xsq[b ^ 1][0] + swzb[i]) = s;
            }
        }

        // rinv transpose into lrinv[b]: C/D col(d)=l15, row(pixel)=lq*4+r
        #pragma unroll
        for (int j = 0; j < 3; ++j)
            #pragma unroll
            for (int r = 0; r < 4; ++r)
                lrinv[b][(lq * 4 + r) * RSTRIDE + d0w + j * 16 + l15] =
                    __builtin_amdgcn_rsqf(acc[j][r] + biasl[j]);

        lds_barrier();  // xsq[b^1] + lrinv[b] visible; xc stays in flight

        // epilogue: out = x(regs) * rinv, fully coalesced
        {
            float* op = out + (size_t)tile * (MBLK * 192);
            #pragma unroll
            for (int i = 0; i < 3; ++i) {
                f32x4 rv = *(const f32x4*)&lrinv[b][lofs[i]];
                f32x4 o;
                #pragma unroll
                for (int h = 0; h < 4; ++h) o[h] = xa[i][h] * rv[h];
                *(f32x4*)(op + tid * 4 + 1024 * i) = o;
            }
        }

        // rotate pipeline
        #pragma unroll
        for (int i = 0; i < 3; ++i) { xa[i] = xb[i]; xb[i] = xc[i]; }
    }
}

extern "C" void kernel_launch(void* const* d_in, const int* in_sizes, int n_in,
                              void* d_out, int out_size, void* d_ws, size_t ws_size,
                              hipStream_t stream)
{
    const float* x           = (const float*)d_in[0];
    const float* beta_raw    = (const float*)d_in[1];
    const float* gamma_raw   = (const float*)d_in[2];
    const float* beta_scale  = (const float*)d_in[3];
    const float* beta_bias   = (const float*)d_in[4];
    const float* gamma_scale = (const float*)d_in[5];
    const float* gamma_bias  = (const float*)d_in[6];
    const int*   idxp        = (const int*)d_in[7];
    float*       out         = (float*)d_out;

    unsigned short* GT    = (unsigned short*)d_ws;
    float*          biasv = (float*)((char*)d_ws + 192 * 192 * sizeof(unsigned short));

    gdn_prep<<<144, 256, 0, stream>>>(beta_raw, gamma_raw, beta_scale, beta_bias,
                                      gamma_scale, gamma_bias, idxp, GT, biasv);

    const int P = out_size / 192;       // 524288 pixels
    const int ntiles = P / MBLK;        // 32768
    gdn_main<<<NBLOCKS, 256, 0, stream>>>(x, GT, biasv, out, ntiles);
}